// Round 6
// baseline (77.079 us; speedup 1.0000x reference)
//
#include <hip/hip_runtime.h>

#define BB 16
#define TT 12
#define NN 10000
#define DD 2
#define EE 320000
#define BT 192              // BB*TT
#define TOT 3840000
#define SLICE 20000         // NN*DD
#define SPATB 2048
#define UPX 120000          // units per XCD = 3*EE/8
#define UPW 118             // ceil(UPX / 1024 waves per XCD)

// prep roles
#define PACKB 942           // 157 node-groups * 3 chunks * 2 halves
#define EOFFB 1250          // EE/256
#define PREPG (PACKB + EOFFB)

// ws layout (fast path):
//   float [0,1024)        main partials per pack tile g (942 used)
//   float [1024,2048)     temporal partials per pack tile
//   float [2048,2048+942*64) cons partials: [g*64 + sl*2 + d]
//   float [65536,67584)   spatial partials per spatial block
//   byte  EOFF_BOFF: uint2 eoffB[EE] = (src*256, dst*256)      2.56 MB
//   byte  W2_BOFF  : u32 w2c[3][NN][64] fp8-packed slots       7.68 MB
#define CONS_F 2048
#define SPAT_F 65536
#define EOFF_BOFF 524288
#define W2_BOFF   3145728
#define NEED (W2_BOFF + (size_t)3 * NN * 64 * 4)

typedef float v2f __attribute__((ext_vector_type(2)));

// ---------------- prep: pack(fp8) + fused main/temporal/cons | eoff ---------
__global__ __launch_bounds__(256) void prep_kernel(const float* __restrict__ p,
                                                   const float* __restrict__ tg,
                                                   const int* __restrict__ idx,
                                                   char* __restrict__ wsb) {
    float* ws = (float*)wsb;
    int g = blockIdx.x;
    if (g >= PACKB) {                                   // ---- eoff role
        int e = (g - PACKB) * 256 + threadIdx.x;
        if (e < EE) {
            uint2* eoffB = (uint2*)(wsb + EOFF_BOFF);
            eoffB[e] = make_uint2((unsigned)idx[e] << 8, (unsigned)idx[EE + e] << 8);
        }
        return;
    }
    // ---- pack + stream role: tile = (chunk c, half sh, 64 nodes)
    __shared__ unsigned tile[64][33];
    __shared__ float red[8];
    int sh = g & 1;
    int t3 = g >> 1;
    int c  = t3 % 3;
    int ng = t3 / 3;
    int n0 = ng * 64;
    int ln = threadIdx.x & 63;
    int r  = threadIdx.x >> 6;              // wave id: slots [8r, 8r+8)
    int n  = n0 + ln;
    int btbase = c * 64 + sh * 32 + r * 8;
    bool valid = (n < NN);

    float4 v[8];
    float m = 0.f;
#pragma unroll
    for (int k = 0; k < 8; ++k) {
        float2 pv = make_float2(0.f, 0.f), tv = make_float2(0.f, 0.f);
        if (valid) {
            size_t e = (size_t)(btbase + k) * SLICE + (size_t)n * 2;
            pv = *reinterpret_cast<const float2*>(p + e);
            tv = *reinterpret_cast<const float2*>(tg + e);
        }
        v[k] = make_float4(pv.x, pv.y, tv.x, tv.y);
        m += fabsf(pv.x - tv.x) + fabsf(pv.y - tv.y);
        int pk = __builtin_amdgcn_cvt_pk_fp8_f32(pv.x, pv.y, 0, false);
        pk = __builtin_amdgcn_cvt_pk_fp8_f32(tv.x, tv.y, pk, true);
        tile[ln][r * 8 + k] = (unsigned)pk;
    }

    // conservation: per-slot wave reduction over the 64 nodes (lanes)
    float cx[8], cy[8];
#pragma unroll
    for (int k = 0; k < 8; ++k) { cx[k] = v[k].x - v[k].z; cy[k] = v[k].y - v[k].w; }
#pragma unroll
    for (int k = 0; k < 8; ++k)
        for (int o = 32; o; o >>= 1) { cx[k] += __shfl_xor(cx[k], o); cy[k] += __shfl_xor(cy[k], o); }
    if (ln == 0) {
        float* cw = ws + CONS_F + g * 64 + r * 16;
#pragma unroll
        for (int k = 0; k < 8; ++k) { cw[2 * k] = cx[k]; cw[2 * k + 1] = cy[k]; }
    }

    __syncthreads();

    // temporal: 7 in-register f32 pairs + 1 boundary pair
    float w = 0.f;
    if (valid) {
#pragma unroll
        for (int k = 0; k < 7; ++k) {
            if ((btbase + k) % TT < TT - 1) {
                float d0 = (v[k + 1].x - v[k].x) - (v[k + 1].z - v[k].z);
                float d1 = (v[k + 1].y - v[k].y) - (v[k + 1].w - v[k].w);
                w = fmaf(d0, d0, w);
                w = fmaf(d1, d1, w);
            }
        }
        int bt7 = btbase + 7;
        if (bt7 % TT < TT - 1) {
            int sl = r * 8 + 7;
            float4 nx;
            if (sl < 31) {                              // neighbor wave's slot, fp8 tile
                unsigned u4 = tile[ln][sl + 1];
                v2f ap = __builtin_amdgcn_cvt_pk_f32_fp8((int)u4, false);
                v2f at = __builtin_amdgcn_cvt_pk_f32_fp8((int)u4, true);
                nx = make_float4(ap[0], ap[1], at[0], at[1]);
            } else {                                    // tile boundary: global f32
                size_t e = (size_t)(bt7 + 1) * SLICE + (size_t)n * 2;
                float2 pv = *reinterpret_cast<const float2*>(p + e);
                float2 tv = *reinterpret_cast<const float2*>(tg + e);
                nx = make_float4(pv.x, pv.y, tv.x, tv.y);
            }
            float d0 = (nx.x - v[7].x) - (nx.z - v[7].z);
            float d1 = (nx.y - v[7].y) - (nx.w - v[7].w);
            w = fmaf(d0, d0, w);
            w = fmaf(d1, d1, w);
        }
    }

    // write packed tile out (node-row-major, coalesced 128B segments)
    unsigned* w2c = (unsigned*)(wsb + W2_BOFF);
    int nn2 = threadIdx.x >> 5;
    int sl2 = threadIdx.x & 31;
    for (int k = nn2; k < 64; k += 8) {
        int n2 = n0 + k;
        if (n2 < NN)
            w2c[((unsigned)(c * NN + n2) << 6) + sh * 32 + sl2] = tile[k][sl2];
    }

    // block-reduce m, w
    for (int o = 32; o; o >>= 1) { m += __shfl_xor(m, o); w += __shfl_xor(w, o); }
    if (ln == 0) { red[r] = m; red[4 + r] = w; }
    __syncthreads();
    if (threadIdx.x == 0) {
        ws[g]        = red[0] + red[1] + red[2] + red[3];
        ws[1024 + g] = red[4] + red[5] + red[6] + red[7];
    }
}

// ---------------- spatial: XCD-pinned, SGPR-base saddr gather ---------------
__global__ __launch_bounds__(256) void spatial_kernel(const char* __restrict__ w2,
                                                      const uint2* __restrict__ eoffB,
                                                      float* __restrict__ ws) {
    int lane  = threadIdx.x & 63;
    int lane4 = lane * 4;
    int xcd = blockIdx.x & 7;              // round-robin XCD map (perf heuristic only)
    int jw  = (blockIdx.x >> 3) * 4 + (threadIdx.x >> 6);
    int rem = UPX - jw * UPW;
    int cnt = rem < 0 ? 0 : (rem < UPW ? rem : UPW);
    int u   = xcd * UPX + jw * UPW;

    float s = 0.f;
    while (cnt > 0) {
        int c = u / EE;
        int e = u - c * EE;
        int seg = (c + 1) * EE - u;
        if (seg > cnt) seg = cnt;
        const char* base = w2 + (size_t)c * (NN * 256);
        const uint2* ep = eoffB + e;
        int k = 0;
        for (; k + 4 <= seg; k += 4) {
            unsigned oa[4], ob[4];
#pragma unroll
            for (int q = 0; q < 4; ++q) {
                uint2 o = ep[k + q];
                oa[q] = (unsigned)__builtin_amdgcn_readfirstlane((int)o.x);
                ob[q] = (unsigned)__builtin_amdgcn_readfirstlane((int)o.y);
            }
            unsigned A[4], B4[4];
#pragma unroll
            for (int q = 0; q < 4; ++q) {
                A[q]  = *reinterpret_cast<const unsigned*>(base + oa[q] + lane4);
                B4[q] = *reinterpret_cast<const unsigned*>(base + ob[q] + lane4);
            }
#pragma unroll
            for (int q = 0; q < 4; ++q) {
                v2f ap = __builtin_amdgcn_cvt_pk_f32_fp8((int)A[q], false);
                v2f at = __builtin_amdgcn_cvt_pk_f32_fp8((int)A[q], true);
                v2f bp = __builtin_amdgcn_cvt_pk_f32_fp8((int)B4[q], false);
                v2f bq = __builtin_amdgcn_cvt_pk_f32_fp8((int)B4[q], true);
                float d0 = fabsf(ap[0] - bp[0]) - fabsf(at[0] - bq[0]);
                float d1 = fabsf(ap[1] - bp[1]) - fabsf(at[1] - bq[1]);
                s = fmaf(d0, d0, s);
                s = fmaf(d1, d1, s);
            }
        }
        for (; k < seg; ++k) {
            uint2 o = ep[k];
            unsigned oa = (unsigned)__builtin_amdgcn_readfirstlane((int)o.x);
            unsigned ob = (unsigned)__builtin_amdgcn_readfirstlane((int)o.y);
            unsigned A  = *reinterpret_cast<const unsigned*>(base + oa + lane4);
            unsigned B4 = *reinterpret_cast<const unsigned*>(base + ob + lane4);
            v2f ap = __builtin_amdgcn_cvt_pk_f32_fp8((int)A, false);
            v2f at = __builtin_amdgcn_cvt_pk_f32_fp8((int)A, true);
            v2f bp = __builtin_amdgcn_cvt_pk_f32_fp8((int)B4, false);
            v2f bq = __builtin_amdgcn_cvt_pk_f32_fp8((int)B4, true);
            float d0 = fabsf(ap[0] - bp[0]) - fabsf(at[0] - bq[0]);
            float d1 = fabsf(ap[1] - bp[1]) - fabsf(at[1] - bq[1]);
            s = fmaf(d0, d0, s);
            s = fmaf(d1, d1, s);
        }
        u += seg;
        cnt -= seg;
    }
    for (int o = 32; o; o >>= 1) s += __shfl_xor(s, o);
    __shared__ float sv[4];
    if (lane == 0) sv[threadIdx.x >> 6] = s;
    __syncthreads();
    if (threadIdx.x == 0) ws[SPAT_F + blockIdx.x] = sv[0] + sv[1] + sv[2] + sv[3];
}

// ---------------- finalize (fast path) --------------------------------------
__global__ __launch_bounds__(1024) void finalize_kernel(const float* __restrict__ ws,
                                                        float* __restrict__ out) {
    int tid = threadIdx.x;
    float a = 0, bv = 0, sp = 0, cq = 0;
    for (int k = tid; k < PACKB; k += 1024) { a += ws[k]; bv += ws[1024 + k]; }
    for (int k = tid; k < SPATB; k += 1024) sp += ws[SPAT_F + k];
    if (tid < BT * DD) {
        int bt = tid >> 1, d = tid & 1;
        int c = bt >> 6, remn = bt & 63, sh = remn >> 5, sl = remn & 31;
        float cs = 0;
        for (int ng = 0; ng < 157; ++ng)
            cs += ws[CONS_F + (((ng * 3 + c) << 1) | sh) * 64 + sl * 2 + d];
        cq = cs * cs;
    }
    for (int o = 32; o; o >>= 1) {
        a += __shfl_xor(a, o); bv += __shfl_xor(bv, o);
        sp += __shfl_xor(sp, o); cq += __shfl_xor(cq, o);
    }
    __shared__ float ra[16], rb[16], rs[16], rc[16];
    int wid = tid >> 6;
    if ((tid & 63) == 0) { ra[wid] = a; rb[wid] = bv; rs[wid] = sp; rc[wid] = cq; }
    __syncthreads();
    if (tid == 0) {
        float A = 0, B2 = 0, S = 0, C = 0;
        for (int k = 0; k < 16; k++) { A += ra[k]; B2 += rb[k]; S += rs[k]; C += rc[k]; }
        float mainl = A / (float)TOT;
        float temp  = B2 / (float)(BB * (TT - 1) * NN * DD);
        float spat  = S / ((float)BT * (float)EE * (float)DD);
        float cons  = C / (float)(BT * DD);
        out[0] = mainl + 0.1f * spat + 0.05f * temp + 0.02f * cons;
        out[1] = mainl; out[2] = spat; out[3] = temp; out[4] = cons;
    }
}

// ================= fallback path (ws too small) =============================
__global__ __launch_bounds__(256) void stream_fb(const float* __restrict__ p,
                                                 const float* __restrict__ tg,
                                                 float* __restrict__ ws) {
    int b = blockIdx.x;
    int bt = b >> 3, part = b & 7;
    int tt = bt % TT;
    size_t base = (size_t)bt * SLICE;
    bool inner = (tt < TT - 1);
    float m = 0.f, w = 0.f, c = 0.f;
    int j0 = part * 2500;
    for (int j = j0 + threadIdx.x; j < j0 + 2500; j += 256) {
        size_t jj = base + j;
        float pv = p[jj], tv = tg[jj];
        m += fabsf(pv - tv);
        c += pv - tv;
        if (inner) {
            float pn = p[jj + SLICE], tn = tg[jj + SLICE];
            float dd = (pn - pv) - (tn - tv);
            w += dd * dd;
        }
    }
    for (int o = 32; o >= 2; o >>= 1) {
        m += __shfl_xor(m, o); w += __shfl_xor(w, o); c += __shfl_xor(c, o);
    }
    m += __shfl_xor(m, 1);
    w += __shfl_xor(w, 1);
    __shared__ float sm[4], sw[4], s0[4], s1[4];
    int wid = threadIdx.x >> 6, lane = threadIdx.x & 63;
    if (lane == 0) { sm[wid] = m; sw[wid] = w; s0[wid] = c; }
    if (lane == 1) { s1[wid] = c; }
    __syncthreads();
    if (threadIdx.x == 0) {
        float a = 0, bv = 0, c0 = 0, c1 = 0;
        for (int k = 0; k < 4; k++) { a += sm[k]; bv += sw[k]; c0 += s0[k]; c1 += s1[k]; }
        ws[70000 + b] = a; ws[72000 + b] = bv;
        ws[74000 + 2 * b] = c0; ws[74000 + 2 * b + 1] = c1;
    }
}

__global__ __launch_bounds__(256) void spatial_fb(const float* __restrict__ p,
                                                  const float* __restrict__ tg,
                                                  const int* __restrict__ idx,
                                                  float* __restrict__ ws) {
    int lane = threadIdx.x & 63;
    int wave = (blockIdx.x * 256 + threadIdx.x) >> 6;
    float s = 0.f;
    for (int e = wave; e < EE; e += SPATB * 4) {
        int sn = idx[e] * DD, dn = idx[EE + e] * DD;
        for (int bt = lane; bt < BT; bt += 64) {
            size_t base = (size_t)bt * SLICE;
            float2 ps = *reinterpret_cast<const float2*>(p + base + sn);
            float2 pd = *reinterpret_cast<const float2*>(p + base + dn);
            float2 ts = *reinterpret_cast<const float2*>(tg + base + sn);
            float2 td = *reinterpret_cast<const float2*>(tg + base + dn);
            float d0 = fabsf(ps.x - pd.x) - fabsf(ts.x - td.x);
            float d1 = fabsf(ps.y - pd.y) - fabsf(ts.y - td.y);
            s = fmaf(d0, d0, s);
            s = fmaf(d1, d1, s);
        }
    }
    for (int o = 32; o; o >>= 1) s += __shfl_xor(s, o);
    __shared__ float sv[4];
    if (lane == 0) sv[threadIdx.x >> 6] = s;
    __syncthreads();
    if (threadIdx.x == 0) ws[SPAT_F + blockIdx.x] = sv[0] + sv[1] + sv[2] + sv[3];
}

__global__ __launch_bounds__(1024) void finalize_fb(const float* __restrict__ ws,
                                                    float* __restrict__ out) {
    int tid = threadIdx.x;
    float a = 0, bv = 0, sp = 0, cq = 0;
    for (int k = tid; k < 1536; k += 1024) { a += ws[70000 + k]; bv += ws[72000 + k]; }
    for (int k = tid; k < SPATB; k += 1024) sp += ws[SPAT_F + k];
    for (int k = tid; k < BT * DD; k += 1024) {
        int bt = k >> 1, par = k & 1;
        float cs = 0;
        for (int part = 0; part < 8; ++part)
            cs += ws[74000 + ((bt * 8 + part) << 1) + par];
        cq += cs * cs;
    }
    for (int o = 32; o; o >>= 1) {
        a += __shfl_xor(a, o); bv += __shfl_xor(bv, o);
        sp += __shfl_xor(sp, o); cq += __shfl_xor(cq, o);
    }
    __shared__ float ra[16], rb[16], rs[16], rc[16];
    int wid = tid >> 6;
    if ((tid & 63) == 0) { ra[wid] = a; rb[wid] = bv; rs[wid] = sp; rc[wid] = cq; }
    __syncthreads();
    if (tid == 0) {
        float A = 0, B2 = 0, S = 0, C = 0;
        for (int k = 0; k < 16; k++) { A += ra[k]; B2 += rb[k]; S += rs[k]; C += rc[k]; }
        float mainl = A / (float)TOT;
        float temp  = B2 / (float)(BB * (TT - 1) * NN * DD);
        float spat  = S / ((float)BT * (float)EE * (float)DD);
        float cons  = C / (float)(BT * DD);
        out[0] = mainl + 0.1f * spat + 0.05f * temp + 0.02f * cons;
        out[1] = mainl; out[2] = spat; out[3] = temp; out[4] = cons;
    }
}

extern "C" void kernel_launch(void* const* d_in, const int* in_sizes, int n_in,
                              void* d_out, int out_size, void* d_ws, size_t ws_size,
                              hipStream_t stream) {
    const float* p  = (const float*)d_in[0];
    const float* tg = (const float*)d_in[1];
    const int*   ix = (const int*)d_in[2];
    float* out = (float*)d_out;
    char*  wsb = (char*)d_ws;
    float* ws  = (float*)d_ws;

    if (ws_size >= NEED) {
        prep_kernel<<<PREPG, 256, 0, stream>>>(p, tg, ix, wsb);
        spatial_kernel<<<SPATB, 256, 0, stream>>>(wsb + W2_BOFF,
                                                  (const uint2*)(wsb + EOFF_BOFF), ws);
        finalize_kernel<<<1, 1024, 0, stream>>>(ws, out);
    } else {
        stream_fb<<<1536, 256, 0, stream>>>(p, tg, ws);
        spatial_fb<<<SPATB, 256, 0, stream>>>(p, tg, ix, ws);
        finalize_fb<<<1, 1024, 0, stream>>>(ws, out);
    }
}

// Round 7
// 68.405 us; speedup vs baseline: 1.1268x; 1.1268x over previous
//
#include <hip/hip_runtime.h>

#define BB 16
#define TT 12
#define NN 10000
#define DD 2
#define EE 320000
#define BT 192              // BB*TT
#define TOT 3840000
#define SLICE 20000         // NN*DD

#define NCH 48              // chunks (4 bt-slots each)
#define SLICES 16           // edge slices
#define EPS 20000           // edges per slice
#define SPATB (NCH*SLICES)  // 768

// prep roles
#define PACKB 942           // 157 node-groups * 6 slot-groups(32)
#define STRB 1536           // stream role blocks
#define EOFFB 1250          // EE/256
#define PREPG (PACKB + STRB + EOFFB)   // 3728

// ws layout:
//   float [0,1536)     main partials        [1536,3072)  temporal partials
//   float [3072,6144)  cons partials        [6144,6912)  spatial partials (768)
//   byte  EOFF_BOFF : u32 eoff[EE] (src | dst<<16)    1.28 MB
//   byte  W2_BOFF   : u32 w2c[48][NN][4] fp8-packed   7.68 MB
#define EOFF_BOFF 32768
#define W2_BOFF   1314816
#define NEED (W2_BOFF + (size_t)NCH * NN * 4 * 4)

typedef float v2f __attribute__((ext_vector_type(2)));

// ---------------- stream body (main/temporal/conservation), proven r5 -------
__device__ __forceinline__ void stream_body(int b, const float* __restrict__ p,
                                            const float* __restrict__ tg,
                                            float* __restrict__ ws) {
    int bt = b >> 3, part = b & 7;
    int tt = bt % TT;
    size_t base = (size_t)bt * SLICE;
    bool inner = (tt < TT - 1);
    float m = 0.f, w = 0.f, c = 0.f;
    int j0 = part * 2500;
    for (int j = j0 + threadIdx.x; j < j0 + 2500; j += 256) {
        size_t jj = base + j;
        float pv = p[jj], tv = tg[jj];
        m += fabsf(pv - tv);
        c += pv - tv;                      // key parity = tid parity
        if (inner) {
            float pn = p[jj + SLICE], tn = tg[jj + SLICE];
            float dd = (pn - pv) - (tn - tv);
            w += dd * dd;
        }
    }
    for (int o = 32; o >= 2; o >>= 1) {
        m += __shfl_xor(m, o); w += __shfl_xor(w, o); c += __shfl_xor(c, o);
    }
    m += __shfl_xor(m, 1);
    w += __shfl_xor(w, 1);
    __shared__ float sm[4], sw[4], s0[4], s1[4];
    int wid = threadIdx.x >> 6, lane = threadIdx.x & 63;
    if (lane == 0) { sm[wid] = m; sw[wid] = w; s0[wid] = c; }
    if (lane == 1) { s1[wid] = c; }
    __syncthreads();
    if (threadIdx.x == 0) {
        float a = 0, bv = 0, c0 = 0, c1 = 0;
        for (int k = 0; k < 4; k++) { a += sm[k]; bv += sw[k]; c0 += s0[k]; c1 += s1[k]; }
        ws[b] = a; ws[1536 + b] = bv;
        ws[3072 + 2 * b] = c0; ws[3072 + 2 * b + 1] = c1;
    }
}

// ---------------- prep: pack(fp8, chunk-major) | stream | eoff --------------
__global__ __launch_bounds__(256) void prep_kernel(const float* __restrict__ p,
                                                   const float* __restrict__ tg,
                                                   const int* __restrict__ idx,
                                                   char* __restrict__ wsb) {
    float* ws = (float*)wsb;
    int g = blockIdx.x;
    if (g < PACKB) {                                    // ---- pack role
        __shared__ unsigned tile[64][33];
        int ng = g / 6, cg = g % 6;                     // 64-node group, 32-slot group
        int n0 = ng * 64;
        int ln = threadIdx.x & 63, r = threadIdx.x >> 6;
        int n = n0 + ln;
        if (n < NN) {
            for (int sl = r; sl < 32; sl += 4) {
                int bt = cg * 32 + sl;
                size_t e = (size_t)bt * SLICE + (size_t)n * 2;
                float2 pv = *reinterpret_cast<const float2*>(p + e);
                float2 tv = *reinterpret_cast<const float2*>(tg + e);
                int pk = __builtin_amdgcn_cvt_pk_fp8_f32(pv.x, pv.y, 0, false);
                pk = __builtin_amdgcn_cvt_pk_fp8_f32(tv.x, tv.y, pk, true);
                tile[ln][sl] = (unsigned)pk;
            }
        }
        __syncthreads();
        unsigned* w2c = (unsigned*)(wsb + W2_BOFF);
        int nl = threadIdx.x >> 2, k = threadIdx.x & 3;
        if (n0 + nl < NN) {
#pragma unroll
            for (int c2 = 0; c2 < 8; ++c2) {            // chunk c = cg*8 + c2
                int c = cg * 8 + c2;
                w2c[((unsigned)(c * NN + n0 + nl) << 2) + k] = tile[nl][c2 * 4 + k];
            }
        }
    } else if (g < PACKB + STRB) {                      // ---- stream role
        stream_body(g - PACKB, p, tg, ws);
    } else {                                            // ---- eoff role
        int e = (g - PACKB - STRB) * 256 + threadIdx.x;
        if (e < EE) {
            unsigned* eoff = (unsigned*)(wsb + EOFF_BOFF);
            eoff[e] = (unsigned)idx[e] | ((unsigned)idx[EE + e] << 16);
        }
    }
}

// ---------------- spatial: LDS-resident chunk, thread-per-edge gather -------
__global__ __launch_bounds__(1024) void spatial_kernel(const uint4* __restrict__ w2c4,
                                                       const unsigned* __restrict__ eoff,
                                                       float* __restrict__ ws) {
    __shared__ uint4 nd[NN];            // 160,000 B: all nodes, this chunk's 4 slots
    __shared__ float red[16];
    int bid = blockIdx.x;
    int c = bid % NCH;                  // chunk: 16 blocks share it, all on XCD c%8
    int s = bid / NCH;                  // edge slice
    const uint4* src = w2c4 + (size_t)c * NN;
    for (int i = threadIdx.x; i < NN; i += 1024)
        nd[i] = src[i];
    __syncthreads();

    int e    = s * EPS + threadIdx.x;
    int eend = s * EPS + EPS;
    float acc = 0.f;
    unsigned eo = eoff[e];              // tid < 1024 <= EPS, always valid
    while (e < eend) {
        int en = e + 1024;
        unsigned eon = (en < eend) ? eoff[en] : 0u;     // prefetch next
        uint4 A = nd[eo & 0xFFFFu];
        uint4 B = nd[eo >> 16];
#pragma unroll
        for (int k = 0; k < 4; ++k) {
            unsigned au = (&A.x)[k], bu = (&B.x)[k];
            v2f ap = __builtin_amdgcn_cvt_pk_f32_fp8((int)au, false);
            v2f at = __builtin_amdgcn_cvt_pk_f32_fp8((int)au, true);
            v2f bp = __builtin_amdgcn_cvt_pk_f32_fp8((int)bu, false);
            v2f bq = __builtin_amdgcn_cvt_pk_f32_fp8((int)bu, true);
            float d0 = fabsf(ap[0] - bp[0]) - fabsf(at[0] - bq[0]);
            float d1 = fabsf(ap[1] - bp[1]) - fabsf(at[1] - bq[1]);
            acc = fmaf(d0, d0, acc);
            acc = fmaf(d1, d1, acc);
        }
        eo = eon;
        e = en;
    }
    for (int o = 32; o; o >>= 1) acc += __shfl_xor(acc, o);
    if ((threadIdx.x & 63) == 0) red[threadIdx.x >> 6] = acc;
    __syncthreads();
    if (threadIdx.x == 0) {
        float t = 0.f;
        for (int k = 0; k < 16; ++k) t += red[k];
        ws[6144 + bid] = t;
    }
}

// ---------------- fallback spatial (ws too small): direct fp32 gather -------
__global__ __launch_bounds__(256) void spatial_fb(const float* __restrict__ p,
                                                  const float* __restrict__ tg,
                                                  const int* __restrict__ idx,
                                                  float* __restrict__ ws) {
    int lane = threadIdx.x & 63;
    int wave = (blockIdx.x * 256 + threadIdx.x) >> 6;
    float s = 0.f;
    for (int e = wave; e < EE; e += SPATB * 4) {
        int sn = idx[e] * DD, dn = idx[EE + e] * DD;
        for (int bt = lane; bt < BT; bt += 64) {
            size_t base = (size_t)bt * SLICE;
            float2 ps = *reinterpret_cast<const float2*>(p + base + sn);
            float2 pd = *reinterpret_cast<const float2*>(p + base + dn);
            float2 ts = *reinterpret_cast<const float2*>(tg + base + sn);
            float2 td = *reinterpret_cast<const float2*>(tg + base + dn);
            float d0 = fabsf(ps.x - pd.x) - fabsf(ts.x - td.x);
            float d1 = fabsf(ps.y - pd.y) - fabsf(ts.y - td.y);
            s = fmaf(d0, d0, s);
            s = fmaf(d1, d1, s);
        }
    }
    for (int o = 32; o; o >>= 1) s += __shfl_xor(s, o);
    __shared__ float sv[4];
    if (lane == 0) sv[threadIdx.x >> 6] = s;
    __syncthreads();
    if (threadIdx.x == 0) ws[6144 + blockIdx.x] = sv[0] + sv[1] + sv[2] + sv[3];
}

__global__ __launch_bounds__(256) void stream_fb(const float* __restrict__ p,
                                                 const float* __restrict__ tg,
                                                 float* __restrict__ ws) {
    stream_body(blockIdx.x, p, tg, ws);
}

// ---------------- finalize (shared by both paths) ---------------------------
__global__ __launch_bounds__(1024) void finalize_kernel(const float* __restrict__ ws,
                                                        float* __restrict__ out) {
    int tid = threadIdx.x;
    float a = 0, bv = 0, sp = 0, cq = 0;
    for (int k = tid; k < STRB; k += 1024) { a += ws[k]; bv += ws[1536 + k]; }
    for (int k = tid; k < SPATB; k += 1024) sp += ws[6144 + k];
    if (tid < BT * DD) {
        int bt = tid >> 1, par = tid & 1;
        float cs = 0;
        for (int part = 0; part < 8; ++part)
            cs += ws[3072 + ((bt * 8 + part) << 1) + par];
        cq = cs * cs;
    }
    for (int o = 32; o; o >>= 1) {
        a += __shfl_xor(a, o); bv += __shfl_xor(bv, o);
        sp += __shfl_xor(sp, o); cq += __shfl_xor(cq, o);
    }
    __shared__ float ra[16], rb[16], rs[16], rc[16];
    int wid = tid >> 6;
    if ((tid & 63) == 0) { ra[wid] = a; rb[wid] = bv; rs[wid] = sp; rc[wid] = cq; }
    __syncthreads();
    if (tid == 0) {
        float A = 0, B2 = 0, S = 0, C = 0;
        for (int k = 0; k < 16; k++) { A += ra[k]; B2 += rb[k]; S += rs[k]; C += rc[k]; }
        float mainl = A / (float)TOT;
        float temp  = B2 / (float)(BB * (TT - 1) * NN * DD);
        float spat  = S / ((float)BT * (float)EE * (float)DD);
        float cons  = C / (float)(BT * DD);
        out[0] = mainl + 0.1f * spat + 0.05f * temp + 0.02f * cons;
        out[1] = mainl; out[2] = spat; out[3] = temp; out[4] = cons;
    }
}

extern "C" void kernel_launch(void* const* d_in, const int* in_sizes, int n_in,
                              void* d_out, int out_size, void* d_ws, size_t ws_size,
                              hipStream_t stream) {
    const float* p  = (const float*)d_in[0];
    const float* tg = (const float*)d_in[1];
    const int*   ix = (const int*)d_in[2];
    float* out = (float*)d_out;
    char*  wsb = (char*)d_ws;
    float* ws  = (float*)d_ws;

    if (ws_size >= NEED) {
        prep_kernel<<<PREPG, 256, 0, stream>>>(p, tg, ix, wsb);
        spatial_kernel<<<SPATB, 1024, 0, stream>>>((const uint4*)(wsb + W2_BOFF),
                                                   (const unsigned*)(wsb + EOFF_BOFF), ws);
    } else {
        stream_fb<<<STRB, 256, 0, stream>>>(p, tg, ws);
        spatial_fb<<<SPATB, 256, 0, stream>>>(p, tg, ix, ws);
    }
    finalize_kernel<<<1, 1024, 0, stream>>>(ws, out);
}